// Round 5
// baseline (1139.268 us; speedup 1.0000x reference)
//
#include <hip/hip_runtime.h>

#define BATCH 1024
#define SEQ   1024
#define FDIM  36
#define HID   20
#define G3    60
#define GIPAD 60
#define NROWS (BATCH*SEQ)
#define PROWS 16   // rows per wave in prep

typedef float v2f __attribute__((ext_vector_type(2)));

__device__ __forceinline__ float fast_sigmoid(float x){
    return __builtin_amdgcn_rcpf(1.0f + __expf(-x));
}
__device__ __forceinline__ float fast_tanh(float x){
    return fmaf(-2.0f, __builtin_amdgcn_rcpf(1.0f + __expf(2.0f*x)), 1.0f);
}

#define READLANE_F(v, u) __int_as_float(__builtin_amdgcn_readlane(__float_as_int(v), (u)))

// ---------------- Kernel 1: embed/concat -> origin, fused gi = Wih1@x + bih1 ----------
// 16 rows/wave, two flat load phases, LDS-broadcast pk-dot.
// gi store layout: [row][u*3 + g]  (u = hidden unit, g = gate) for the unit-major GRU enc.
template<bool WRITE_GI>
__global__ __launch_bounds__(256, 4)
void prep_kernel(const float* __restrict__ x,
                 const int* __restrict__ oh,
                 const float* __restrict__ e0, const float* __restrict__ e1,
                 const float* __restrict__ e2, const float* __restrict__ e3,
                 const float* __restrict__ Wih1g, const float* __restrict__ bih1g,
                 float* __restrict__ origin, float* __restrict__ gibuf)
{
    __shared__ __align__(16) float xsh[4][64];
    const int lane  = threadIdx.x & 63;
    const int wslot = threadIdx.x >> 6;
    const int w = blockIdx.x * 4 + wslot;
    const int r0 = w * PROWS;

    // per-lane gather descriptor
    const int j = lane;
    const float* tbl; int ohc, eshift, sub;
    if (j < 16)      { tbl = e0; ohc = 0; eshift = 2; sub = j - 12; }
    else if (j < 20) { tbl = e1; ohc = 1; eshift = 2; sub = j - 16; }
    else if (j < 28) { tbl = e2; ohc = 2; eshift = 3; sub = j - 20; }
    else             { tbl = e3; ohc = 3; eshift = 3; sub = j - 28; }
    if (sub < 0) sub = 0;
    if (sub > 7) sub = 7;
    const bool from_x = (j < 12);
    const float* pa = from_x ? (x + j) : (tbl + sub);

    v2f w1p[FDIM/2]; float bi = 0.f;
    const int k = lane < G3 ? lane : G3 - 1;
    const int gidx = (k % HID) * 3 + (k / HID);   // unit-major gi layout
    if (WRITE_GI) {
        #pragma unroll
        for (int q = 0; q < FDIM/2; q++) w1p[q] = ((const v2f*)(Wih1g + k * FDIM))[q];
        bi = bih1g[k];
    }

    // phase 1: all 16 oh loads
    int ohv[PROWS];
    #pragma unroll
    for (int s = 0; s < PROWS; s++) ohv[s] = oh[(r0 + s) * 4 + ohc];
    // phase 2: all 16 gather loads
    float valv[PROWS];
    #pragma unroll
    for (int s = 0; s < PROWS; s++) {
        int off = from_x ? ((r0 + s) * 12) : (ohv[s] << eshift);
        valv[s] = pa[off];
    }

    // phase 3: per-row broadcast + dot + stores
    const float4* xp4 = (const float4*)xsh[wslot];
    #pragma unroll
    for (int s = 0; s < PROWS; s++) {
        const int row = r0 + s;
        if (lane < FDIM) origin[row * FDIM + lane] = valv[s];
        if (WRITE_GI) {
            xsh[wslot][lane] = valv[s];              // DS ops in-order within wave
            v2f a0 = {bi, 0.f}, a1 = {0.f, 0.f};
            #pragma unroll
            for (int q = 0; q < 9; q++) {
                float4 xv4 = xp4[q];
                v2f xlo = {xv4.x, xv4.y}, xhi = {xv4.z, xv4.w};
                a0 = __builtin_elementwise_fma(w1p[2*q],     xlo, a0);
                a1 = __builtin_elementwise_fma(w1p[2*q + 1], xhi, a1);
            }
            float g = (a0.x + a1.x) + (a0.y + a1.y);
            if (lane < G3) gibuf[row * GIPAD + gidx] = g;
        }
    }
}

// ---------------- Kernel 2: encoder GRU + decoder GRU, one wave per batch ----------------
// ENCODER (unit-major, zero LDS/bpermute): lane u<20 owns hidden unit u, computes all
// three gate dots locally (SGPR-broadcast h via readlane). Only cross-lane op: 20 readlanes.
// DECODER (gate-row-major, as R3): lane k<60 owns gate-row k; x via LDS broadcast + pk_fma.
template<bool USE_GI>
__global__ __launch_bounds__(256, 1)
void gru_kernel(const float* __restrict__ xin,
                const float* __restrict__ gibuf,
                const float* __restrict__ Wih1g, const float* __restrict__ Whh1g,
                const float* __restrict__ bih1g, const float* __restrict__ bhh1g,
                const float* __restrict__ Wih2g, const float* __restrict__ Whh2g,
                const float* __restrict__ bih2g, const float* __restrict__ bhh2g,
                const float* __restrict__ Wfcg,  const float* __restrict__ bfcg,
                float* __restrict__ out2)
{
    __shared__ __align__(16) float xsh[4][64];
    const int lane  = threadIdx.x & 63;
    const int wslot = threadIdx.x >> 6;
    const int b = __builtin_amdgcn_readfirstlane(blockIdx.x * 4 + wslot);

    const int k  = lane < G3   ? lane : G3 - 1;     // decoder gate-row
    const int kf = lane < FDIM ? lane : FDIM - 1;   // fc row
    const int u20 = lane < HID ? lane : HID - 1;    // encoder hidden unit

    // encoder weights: rows u, 20+u, 40+u of Whh1 (r,z,n)
    float whr[HID], whz[HID], whn[HID];
    #pragma unroll
    for (int u = 0; u < HID; u++) {
        whr[u] = Whh1g[u20 * HID + u];
        whz[u] = Whh1g[(HID + u20) * HID + u];
        whn[u] = Whh1g[(2 * HID + u20) * HID + u];
    }
    const float bhr = bhh1g[u20], bhz = bhh1g[HID + u20], bhn = bhh1g[2 * HID + u20];

    // decoder weights (gate-row major)
    float whh2[HID], wfc[HID];
    v2f wih2p[FDIM/2];
    #pragma unroll
    for (int q = 0; q < FDIM/2; q++) wih2p[q] = ((const v2f*)(Wih2g + k * FDIM))[q];
    #pragma unroll
    for (int u = 0; u < HID; u++) whh2[u] = Whh2g[k * HID + u];
    #pragma unroll
    for (int u = 0; u < HID; u++) wfc[u] = Wfcg[kf * HID + u];
    const float bi2 = bih2g[k], bh2 = bhh2g[k];
    const float bf  = bfcg[kf];

    float hs[HID];
    #pragma unroll
    for (int u = 0; u < HID; u++) hs[u] = 0.0f;
    float hv = 0.0f;

#define ENC_GATES(GIR, GIZ, GIN) do {                                        \
        float a0 = bhr, a1 = 0.f, a2 = 0.f, a3 = 0.f;                        \
        float c0 = bhz, c1 = 0.f, c2 = 0.f, c3 = 0.f;                        \
        float d0 = bhn, d1 = 0.f, d2 = 0.f, d3 = 0.f;                        \
        _Pragma("unroll")                                                    \
        for (int uu = 0; uu < HID; uu += 4) {                                \
            a0 = fmaf(whr[uu + 0], hs[uu + 0], a0);                          \
            a1 = fmaf(whr[uu + 1], hs[uu + 1], a1);                          \
            a2 = fmaf(whr[uu + 2], hs[uu + 2], a2);                          \
            a3 = fmaf(whr[uu + 3], hs[uu + 3], a3);                          \
            c0 = fmaf(whz[uu + 0], hs[uu + 0], c0);                          \
            c1 = fmaf(whz[uu + 1], hs[uu + 1], c1);                          \
            c2 = fmaf(whz[uu + 2], hs[uu + 2], c2);                          \
            c3 = fmaf(whz[uu + 3], hs[uu + 3], c3);                          \
            d0 = fmaf(whn[uu + 0], hs[uu + 0], d0);                          \
            d1 = fmaf(whn[uu + 1], hs[uu + 1], d1);                          \
            d2 = fmaf(whn[uu + 2], hs[uu + 2], d2);                          \
            d3 = fmaf(whn[uu + 3], hs[uu + 3], d3);                          \
        }                                                                    \
        float ghr = (a0 + a1) + (a2 + a3);                                   \
        float ghz = (c0 + c1) + (c2 + c3);                                   \
        float ghn = (d0 + d1) + (d2 + d3);                                   \
        float r = fast_sigmoid((GIR) + ghr);                                 \
        float z = fast_sigmoid((GIZ) + ghz);                                 \
        float n = fast_tanh(fmaf(r, ghn, (GIN)));                            \
        hv = n + z * (hv - n);                                               \
        _Pragma("unroll")                                                    \
        for (int uu = 0; uu < HID; uu++) hs[uu] = READLANE_F(hv, uu);        \
    } while (0)

    // ---------------- encoder ----------------
    if (USE_GI) {
        const float* gp = gibuf + (size_t)b * SEQ * GIPAD + u20 * 3;
        float q0[4], q1[4], q2[4];
        #pragma unroll
        for (int s = 0; s < 4; s++) {
            const float* pp = gp + s * GIPAD;
            q0[s] = pp[0]; q1[s] = pp[1]; q2[s] = pp[2];
        }
        for (int t = 0; t < SEQ; t += 4) {
            #pragma unroll
            for (int ss = 0; ss < 4; ss++) {
                float gir = q0[ss], giz = q1[ss], gin = q2[ss];
                int tn = t + ss + 4; tn = tn < SEQ ? tn : SEQ - 1;  // uniform clamp
                const float* pp = gp + (size_t)tn * GIPAD;
                q0[ss] = pp[0]; q1[ss] = pp[1]; q2[ss] = pp[2];
                ENC_GATES(gir, giz, gin);
            }
        }
    } else {
        // fallback: in-loop input dots (unit-major: 3x36 FMA per step)
        float wir[FDIM], wiz[FDIM], win[FDIM];
        #pragma unroll
        for (int jj = 0; jj < FDIM; jj++) {
            wir[jj] = Wih1g[u20 * FDIM + jj];
            wiz[jj] = Wih1g[(HID + u20) * FDIM + jj];
            win[jj] = Wih1g[(2 * HID + u20) * FDIM + jj];
        }
        const float bir = bih1g[u20], biz = bih1g[HID + u20], bin = bih1g[2 * HID + u20];
        const float* xbase = xin + (size_t)b * SEQ * FDIM;
        for (int t = 0; t < SEQ; t++) {
            const float* p = xbase + (size_t)t * FDIM;
            float xa[FDIM];
            #pragma unroll
            for (int jj = 0; jj < FDIM; jj++) xa[jj] = p[jj];
            float gr = bir, gz = biz, gn = bin;
            #pragma unroll
            for (int jj = 0; jj < FDIM; jj++) {
                gr = fmaf(wir[jj], xa[jj], gr);
                gz = fmaf(wiz[jj], xa[jj], gz);
                gn = fmaf(win[jj], xa[jj], gn);
            }
            ENC_GATES(gr, gz, gn);
        }
    }

    // ---------------- handoff ----------------
    float hvd = fast_tanh(hv);
    #pragma unroll
    for (int u = 0; u < HID; u++) hs[u] = READLANE_F(hvd, u);

    float* orow = out2 + ((size_t)b * SEQ + (SEQ - 1)) * FDIM;

    float xv;
    {
        float a0 = bf, a1 = 0.f, a2 = 0.f, a3 = 0.f;
        #pragma unroll
        for (int u = 0; u < HID; u += 4) {
            a0 = fmaf(wfc[u + 0], hs[u + 0], a0);
            a1 = fmaf(wfc[u + 1], hs[u + 1], a1);
            a2 = fmaf(wfc[u + 2], hs[u + 2], a2);
            a3 = fmaf(wfc[u + 3], hs[u + 3], a3);
        }
        xv = fast_tanh((a0 + a1) + (a2 + a3));
    }
    if (lane < FDIM) orow[lane] = xv;
    xsh[wslot][lane] = xv;     // intra-wave broadcast (no barrier: same wave)

    // ---------------- decoder (gate-row major, as R3) ----------------
    const v2f* xp = (const v2f*)xsh[wslot];
    for (int d = 1; d < SEQ; ++d) {
        orow -= FDIM;
        v2f xs2[FDIM/2];
        #pragma unroll
        for (int q = 0; q < FDIM/2; q++) xs2[q] = xp[q];
        float h0 = bh2, h1 = 0.f, h2 = 0.f, h3 = 0.f;
        #pragma unroll
        for (int u = 0; u < HID; u += 4) {
            h0 = fmaf(whh2[u + 0], hs[u + 0], h0);
            h1 = fmaf(whh2[u + 1], hs[u + 1], h1);
            h2 = fmaf(whh2[u + 2], hs[u + 2], h2);
            h3 = fmaf(whh2[u + 3], hs[u + 3], h3);
        }
        float gh = (h0 + h1) + (h2 + h3);
        v2f accA = {bi2, 0.f}, accB = {0.f, 0.f};
        #pragma unroll
        for (int q = 0; q < FDIM/2; q += 2) {
            accA = __builtin_elementwise_fma(wih2p[q],     xs2[q],     accA);
            accB = __builtin_elementwise_fma(wih2p[q + 1], xs2[q + 1], accB);
        }
        float gi = (accA.x + accB.x) + (accA.y + accB.y);
        float v   = gi + gh;
        float vz  = __shfl(v,  (lane + 20) & 63);
        float in_ = __shfl(gi, (lane + 40) & 63);
        float hn  = __shfl(gh, (lane + 40) & 63);
        float r = fast_sigmoid(v);
        float z = fast_sigmoid(vz);
        float n = fast_tanh(fmaf(r, hn, in_));
        float hraw = n + z * (hvd - n);
        hvd = fast_tanh(hraw);
        #pragma unroll
        for (int u = 0; u < HID; u++) hs[u] = READLANE_F(hvd, u);
        float a0 = bf, a1 = 0.f, a2 = 0.f, a3 = 0.f;
        #pragma unroll
        for (int u = 0; u < HID; u += 4) {
            a0 = fmaf(wfc[u + 0], hs[u + 0], a0);
            a1 = fmaf(wfc[u + 1], hs[u + 1], a1);
            a2 = fmaf(wfc[u + 2], hs[u + 2], a2);
            a3 = fmaf(wfc[u + 3], hs[u + 3], a3);
        }
        xv = fast_tanh((a0 + a1) + (a2 + a3));
        if (lane < FDIM) orow[lane] = xv;
        xsh[wslot][lane] = xv;
    }
}

extern "C" void kernel_launch(void* const* d_in, const int* in_sizes, int n_in,
                              void* d_out, int out_size, void* d_ws, size_t ws_size,
                              hipStream_t stream) {
    const float* x    = (const float*)d_in[0];
    const int*   oh   = (const int*)d_in[1];
    const float* e0   = (const float*)d_in[2];
    const float* e1   = (const float*)d_in[3];
    const float* e2   = (const float*)d_in[4];
    const float* e3   = (const float*)d_in[5];
    const float* Wih1 = (const float*)d_in[6];
    const float* Whh1 = (const float*)d_in[7];
    const float* bih1 = (const float*)d_in[8];
    const float* bhh1 = (const float*)d_in[9];
    const float* Wih2 = (const float*)d_in[10];
    const float* Whh2 = (const float*)d_in[11];
    const float* bih2 = (const float*)d_in[12];
    const float* bhh2 = (const float*)d_in[13];
    const float* Wfc  = (const float*)d_in[14];
    const float* bfc  = (const float*)d_in[15];

    float* out    = (float*)d_out;
    float* origin = out;
    float* out2   = out + (size_t)BATCH * SEQ * FDIM;
    float* gibuf  = (float*)d_ws;

    const size_t gi_bytes = (size_t)BATCH * SEQ * GIPAD * sizeof(float);
    const int prep_blocks = NROWS / (4 * PROWS);

    if (ws_size >= gi_bytes) {
        prep_kernel<true><<<prep_blocks, 256, 0, stream>>>(x, oh, e0, e1, e2, e3,
                                                           Wih1, bih1, origin, gibuf);
        gru_kernel<true><<<(BATCH * 64) / 256, 256, 0, stream>>>(origin, gibuf,
            Wih1, Whh1, bih1, bhh1, Wih2, Whh2, bih2, bhh2, Wfc, bfc, out2);
    } else {
        prep_kernel<false><<<prep_blocks, 256, 0, stream>>>(x, oh, e0, e1, e2, e3,
                                                            Wih1, bih1, origin, gibuf);
        gru_kernel<false><<<(BATCH * 64) / 256, 256, 0, stream>>>(origin, gibuf,
            Wih1, Whh1, bih1, bhh1, Wih2, Whh2, bih2, bhh2, Wfc, bfc, out2);
    }
}